// Round 1
// baseline (488.945 us; speedup 1.0000x reference)
//
#include <hip/hip_runtime.h>
#include <hip/hip_bf16.h>

// ---------- types ----------
using short8  = __attribute__((ext_vector_type(8))) short;
using ushort8 = __attribute__((ext_vector_type(8))) unsigned short;
using f32x4   = __attribute__((ext_vector_type(4))) float;

#define GLB(p) ((const __attribute__((address_space(1))) void*)(p))
#define LDSP(p) ((__attribute__((address_space(3))) void*)(p))

static __device__ __forceinline__ unsigned short f2bf(float f) {
    union { float f; unsigned u; } v; v.f = f;
    unsigned u = v.u;
    u += 0x7fffu + ((u >> 16) & 1u);   // round-to-nearest-even
    return (unsigned short)(u >> 16);
}

// ---------- problem constants ----------
#define K_DIM 2048
#define N_DIM 2048
#define M_TOTAL 26112
#define N_GROUPS 8
// group sizes: 4096,2048,1024,8192,512,3072,6144,1024 ; offsets below

// ---------- kernel 1: fp32 -> bf16 convert (A groups into contiguous Acat) ----------
__global__ __launch_bounds__(256) void cvt_a_kernel(const float* __restrict__ src,
                                                    unsigned short* __restrict__ dst) {
    long i = ((long)blockIdx.x * 256 + threadIdx.x) * 8;
    float4 x = *(const float4*)(src + i);
    float4 y = *(const float4*)(src + i + 4);
    ushort8 o;
    o[0] = f2bf(x.x); o[1] = f2bf(x.y); o[2] = f2bf(x.z); o[3] = f2bf(x.w);
    o[4] = f2bf(y.x); o[5] = f2bf(y.y); o[6] = f2bf(y.z); o[7] = f2bf(y.w);
    *(ushort8*)(dst + i) = o;
}

// ---------- kernel 2: B [K][N] fp32 -> Bt [N][K] bf16 (transpose + convert) ----------
__global__ __launch_bounds__(256) void cvt_bt_kernel(const float* __restrict__ B,
                                                     unsigned short* __restrict__ Bt) {
    __shared__ float t[32][33];
    int bx = blockIdx.x;              // n tile
    int by = blockIdx.y;              // k tile
    int tx = threadIdx.x;             // 0..31
    int ty = threadIdx.y;             // 0..7
#pragma unroll
    for (int i = 0; i < 32; i += 8)
        t[ty + i][tx] = B[(long)(by * 32 + ty + i) * N_DIM + bx * 32 + tx];
    __syncthreads();
#pragma unroll
    for (int i = 0; i < 32; i += 8)
        Bt[(long)(bx * 32 + ty + i) * K_DIM + by * 32 + tx] = f2bf(t[tx][ty + i]);
}

// ---------- kernel 3: main bf16 GEMM, m97 structure (128x128 tile, BK=32) ----------
// C[M_TOTAL][N] fp32 = Acat[M_TOTAL][K] bf16  *  Bt[N][K]^T bf16
__global__ __launch_bounds__(256) void gemm_bf16_kernel(const unsigned short* __restrict__ Acat,
                                                        const unsigned short* __restrict__ Bt,
                                                        float* __restrict__ C) {
    // grid = 3264 blocks = 204 mtiles * 16 ntiles ; bijective XCD swizzle (3264 % 8 == 0)
    int wg  = blockIdx.x;
    int swz = (wg & 7) * (3264 / 8) + (wg >> 3);
    int mt  = swz >> 4;      // / 16
    int nt  = swz & 15;
    int m0  = mt * 128, n0 = nt * 128;

    int tid = threadIdx.x;
    int l   = tid & 63;
    int w   = tid >> 6;          // wave 0..3
    int wm  = w >> 1;            // wave row 0..1
    int wn  = w & 1;             // wave col 0..1

    __shared__ unsigned short As[128 * 32];   // [row][k] bf16
    __shared__ unsigned short Bs[128 * 32];   // [col][k] bf16 (already transposed)

    // staging: 512 chunks of 16B per tile; chunk = it*256 + tid; row = chunk>>2, c = chunk&3
    int srow = tid >> 2;
    int sc   = tid & 3;
    const unsigned short* ga0 = Acat + (long)(m0 + srow) * K_DIM + sc * 8;
    const unsigned short* ga1 = ga0 + (long)64 * K_DIM;
    const unsigned short* gb0 = Bt   + (long)(n0 + srow) * K_DIM + sc * 8;
    const unsigned short* gb1 = gb0 + (long)64 * K_DIM;
    unsigned short* la0 = As + w * 512;           // wave-uniform LDS bases (HW adds lane*16B)
    unsigned short* la1 = As + 2048 + w * 512;
    unsigned short* lb0 = Bs + w * 512;
    unsigned short* lb1 = Bs + 2048 + w * 512;

    // fragment read addresses
    int r16 = l & 15;
    int kc  = l >> 4;
    const unsigned short* pa = As + (wm * 64 + r16) * 32 + kc * 8;
    const unsigned short* pb = Bs + (wn * 64 + r16) * 32 + kc * 8;

    f32x4 acc[4][4] = {};

    for (int kt = 0; kt < K_DIM; kt += 32) {
        __builtin_amdgcn_global_load_lds(GLB(ga0 + kt), LDSP(la0), 16, 0, 0);
        __builtin_amdgcn_global_load_lds(GLB(ga1 + kt), LDSP(la1), 16, 0, 0);
        __builtin_amdgcn_global_load_lds(GLB(gb0 + kt), LDSP(lb0), 16, 0, 0);
        __builtin_amdgcn_global_load_lds(GLB(gb1 + kt), LDSP(lb1), 16, 0, 0);
        __syncthreads();

        short8 a[4], b[4];
#pragma unroll
        for (int i = 0; i < 4; ++i) a[i] = *(const short8*)(pa + i * 16 * 32);
#pragma unroll
        for (int j = 0; j < 4; ++j) b[j] = *(const short8*)(pb + j * 16 * 32);
#pragma unroll
        for (int i = 0; i < 4; ++i)
#pragma unroll
            for (int j = 0; j < 4; ++j)
                acc[i][j] = __builtin_amdgcn_mfma_f32_16x16x32_bf16(a[i], b[j], acc[i][j], 0, 0, 0);
        __syncthreads();
    }

    // epilogue: C/D layout (16x16x32): col = lane&15, row = (lane>>4)*4 + reg
    int orow = m0 + wm * 64 + (l >> 4) * 4;
    int ocol = n0 + wn * 64 + (l & 15);
#pragma unroll
    for (int i = 0; i < 4; ++i)
#pragma unroll
        for (int j = 0; j < 4; ++j)
#pragma unroll
            for (int q = 0; q < 4; ++q)
                C[(long)(orow + i * 16 + q) * N_DIM + (ocol + j * 16)] = acc[i][j][q];
}

// ---------- fallback: correct (slow) fp32 tiled GEMM, used only if ws too small ----------
__global__ void naive_gemm_kernel(const float* __restrict__ A, const float* __restrict__ B,
                                  float* __restrict__ C, int M) {
    __shared__ float As[16][16];
    __shared__ float Bs[16][17];
    int tx = threadIdx.x, ty = threadIdx.y;
    int row = blockIdx.y * 16 + ty;
    int col = blockIdx.x * 16 + tx;
    float s = 0.f;
    for (int k0 = 0; k0 < K_DIM; k0 += 16) {
        As[ty][tx] = A[(long)row * K_DIM + k0 + tx];
        Bs[ty][tx] = B[(long)(k0 + ty) * N_DIM + col];
        __syncthreads();
#pragma unroll
        for (int t = 0; t < 16; ++t) s += As[ty][t] * Bs[t][tx];
        __syncthreads();
    }
    C[(long)row * N_DIM + col] = s;
}

// ---------- host launcher ----------
extern "C" void kernel_launch(void* const* d_in, const int* in_sizes, int n_in,
                              void* d_out, int out_size, void* d_ws, size_t ws_size,
                              hipStream_t stream) {
    static const int g_m[N_GROUPS]   = {4096, 2048, 1024, 8192, 512, 3072, 6144, 1024};
    static const int g_off[N_GROUPS] = {0, 4096, 6144, 7168, 15360, 15872, 18944, 25088};

    float* C = (float*)d_out;
    const size_t need = ((size_t)M_TOTAL * K_DIM + (size_t)N_DIM * K_DIM) * 2;

    if (ws_size >= need) {
        unsigned short* Acat = (unsigned short*)d_ws;
        unsigned short* Bt   = Acat + (size_t)M_TOTAL * K_DIM;

        // convert the 8 A groups into contiguous bf16 Acat
        for (int g = 0; g < N_GROUPS; ++g) {
            // each thread handles 8 floats; m*2048/(256*8) = m blocks
            cvt_a_kernel<<<g_m[g], 256, 0, stream>>>((const float*)d_in[g],
                                                     Acat + (size_t)g_off[g] * K_DIM);
        }
        // transpose+convert B -> Bt[N][K]
        cvt_bt_kernel<<<dim3(N_DIM / 32, K_DIM / 32), dim3(32, 8), 0, stream>>>(
            (const float*)d_in[8], Bt);

        // main GEMM: 204 mtiles * 16 ntiles
        gemm_bf16_kernel<<<(M_TOTAL / 128) * (N_DIM / 128), 256, 0, stream>>>(Acat, Bt, C);
    } else {
        // ws too small: correct fp32 fallback (slow)
        for (int g = 0; g < N_GROUPS; ++g) {
            naive_gemm_kernel<<<dim3(N_DIM / 16, g_m[g] / 16), dim3(16, 16), 0, stream>>>(
                (const float*)d_in[g], (const float*)d_in[8], C + (size_t)g_off[g] * N_DIM,
                g_m[g]);
        }
    }
}

// Round 2
// 307.345 us; speedup vs baseline: 1.5909x; 1.5909x over previous
//
#include <hip/hip_runtime.h>
#include <hip/hip_bf16.h>

// ---------- types ----------
using short8  = __attribute__((ext_vector_type(8))) short;
using ushort8 = __attribute__((ext_vector_type(8))) unsigned short;
using f32x4   = __attribute__((ext_vector_type(4))) float;

#define GLB(p)  ((const __attribute__((address_space(1))) void*)(p))
#define LDSP(p) ((__attribute__((address_space(3))) void*)(p))

static __device__ __forceinline__ unsigned short f2bf(float f) {
    union { float f; unsigned u; } v; v.f = f;
    unsigned u = v.u;
    u += 0x7fffu + ((u >> 16) & 1u);   // round-to-nearest-even
    return (unsigned short)(u >> 16);
}

// ---------- problem constants ----------
#define K_DIM 2048
#define N_DIM 2048
#define M_TOTAL 26112
#define N_GROUPS 8

// ---------- kernel 1: fp32 -> bf16 convert (A groups into contiguous Acat) ----------
__global__ __launch_bounds__(256) void cvt_a_kernel(const float* __restrict__ src,
                                                    unsigned short* __restrict__ dst) {
    long i = ((long)blockIdx.x * 256 + threadIdx.x) * 8;
    float4 x = *(const float4*)(src + i);
    float4 y = *(const float4*)(src + i + 4);
    ushort8 o;
    o[0] = f2bf(x.x); o[1] = f2bf(x.y); o[2] = f2bf(x.z); o[3] = f2bf(x.w);
    o[4] = f2bf(y.x); o[5] = f2bf(y.y); o[6] = f2bf(y.z); o[7] = f2bf(y.w);
    *(ushort8*)(dst + i) = o;
}

// ---------- kernel 2: B [K][N] fp32 -> Bt [N][K] bf16 (transpose + convert) ----------
__global__ __launch_bounds__(256) void cvt_bt_kernel(const float* __restrict__ B,
                                                     unsigned short* __restrict__ Bt) {
    __shared__ float t[32][33];
    int bx = blockIdx.x, by = blockIdx.y;
    int tx = threadIdx.x, ty = threadIdx.y;
#pragma unroll
    for (int i = 0; i < 32; i += 8)
        t[ty + i][tx] = B[(long)(by * 32 + ty + i) * N_DIM + bx * 32 + tx];
    __syncthreads();
#pragma unroll
    for (int i = 0; i < 32; i += 8)
        Bt[(long)(bx * 32 + ty + i) * K_DIM + by * 32 + tx] = f2bf(t[tx][ty + i]);
}

// ---------- kernel 3: 256x256 8-phase bf16 GEMM (T1+T2+T3+T4+T5) ----------
// C[M_TOTAL][N] fp32 = Acat[M][K] bf16 * Bt[N][K]^T bf16.  BK=64, 8 waves (2Mx4N),
// 128 KiB LDS double buffer, raw s_barrier, counted vmcnt(6) at tile boundaries only,
// XOR-swizzled LDS (pre-swizzled global src + swizzled ds_read; linear gload_lds dest).

#define PBAR() __builtin_amdgcn_s_barrier()
#define LGKM0() asm volatile("s_waitcnt lgkmcnt(0)" ::: "memory")
#define VMC(n)  asm volatile("s_waitcnt vmcnt(" #n ")" ::: "memory")

// stage one 16B/lane load: half H (0/1), sub-load L (0/1) of tile TT into buffer BUF
#define ST_A(BUF, H, L, TT)                                                        \
    __builtin_amdgcn_global_load_lds(                                              \
        GLB(aSt + (long)((H) * 128 + (L) * 64) * K_DIM + (TT) * 64),               \
        LDSP(lds + (BUF) * 32768 + (H) * 8192 + (L) * 4096 + w * 512), 16, 0, 0)
#define ST_B(BUF, H, L, TT)                                                        \
    __builtin_amdgcn_global_load_lds(                                              \
        GLB(bSt + (long)((H) * 128 + (L) * 64) * K_DIM + (TT) * 64),               \
        LDSP(lds + (BUF) * 32768 + 16384 + (H) * 8192 + (L) * 4096 + w * 512), 16, 0, 0)

// one K-tile (BK=64) = 4 phases. DO1: stage A-half1 of tile T+1 (other buffer).
// DO2: stage A-half0/B-half0/B-half1 of tile T+2 (this buffer).
// Region safety: every stage targets a region whose ds_reads finished >=1 barrier earlier.
#define TILE(BUF, T, DO1, DO2)                                                          \
    do {                                                                                \
        const unsigned short* pA = lds + (BUF) * 32768 + wm * 1024 + r16 * 64;          \
        const unsigned short* pB = lds + (BUF) * 32768 + 16384 + wn * 1024 + r16 * 64;  \
        short8 a0[4], a1[4], b00[2], b01[2], b10[2], b11[2];                            \
        /* ---- phase 1: read A-half0 (8) + B-half0 (4); MFMA m0n0 ---- */              \
        _Pragma("unroll") for (int i = 0; i < 4; ++i) {                                 \
            a0[i] = *(const short8*)(pA + i * 2048 + c0 * 8);                           \
            a1[i] = *(const short8*)(pA + i * 2048 + c1 * 8);                           \
        }                                                                               \
        _Pragma("unroll") for (int j = 0; j < 2; ++j) {                                 \
            b00[j] = *(const short8*)(pB + j * 4096 + c0 * 8);                          \
            b01[j] = *(const short8*)(pB + j * 4096 + c1 * 8);                          \
        }                                                                               \
        if (DO1) { ST_A((BUF) ^ 1, 1, 0, (T) + 1); ST_A((BUF) ^ 1, 1, 1, (T) + 1); }    \
        PBAR(); LGKM0();                                                                \
        __builtin_amdgcn_s_setprio(1);                                                  \
        _Pragma("unroll") for (int j = 0; j < 2; ++j)                                   \
        _Pragma("unroll") for (int i = 0; i < 4; ++i) {                                 \
            acc[i][j] = __builtin_amdgcn_mfma_f32_16x16x32_bf16(a0[i], b00[j], acc[i][j], 0, 0, 0); \
            acc[i][j] = __builtin_amdgcn_mfma_f32_16x16x32_bf16(a1[i], b01[j], acc[i][j], 0, 0, 0); \
        }                                                                               \
        __builtin_amdgcn_s_setprio(0); PBAR();                                          \
        /* ---- phase 2: read B-half1 (4); MFMA m0n1 ---- */                            \
        _Pragma("unroll") for (int j = 0; j < 2; ++j) {                                 \
            b10[j] = *(const short8*)(pB + 8192 + j * 4096 + c0 * 8);                   \
            b11[j] = *(const short8*)(pB + 8192 + j * 4096 + c1 * 8);                   \
        }                                                                               \
        if (DO2) { ST_A((BUF), 0, 0, (T) + 2); ST_A((BUF), 0, 1, (T) + 2); }            \
        PBAR(); LGKM0();                                                                \
        __builtin_amdgcn_s_setprio(1);                                                  \
        _Pragma("unroll") for (int j = 0; j < 2; ++j)                                   \
        _Pragma("unroll") for (int i = 0; i < 4; ++i) {                                 \
            acc[i][j + 2] = __builtin_amdgcn_mfma_f32_16x16x32_bf16(a0[i], b10[j], acc[i][j + 2], 0, 0, 0); \
            acc[i][j + 2] = __builtin_amdgcn_mfma_f32_16x16x32_bf16(a1[i], b11[j], acc[i][j + 2], 0, 0, 0); \
        }                                                                               \
        __builtin_amdgcn_s_setprio(0); PBAR();                                          \
        /* ---- phase 3: read A-half1 (8); MFMA m1n0 (b00/b01 still live) ---- */       \
        _Pragma("unroll") for (int i = 0; i < 4; ++i) {                                 \
            a0[i] = *(const short8*)(pA + 8192 + i * 2048 + c0 * 8);                    \
            a1[i] = *(const short8*)(pA + 8192 + i * 2048 + c1 * 8);                    \
        }                                                                               \
        if (DO2) { ST_B((BUF), 0, 0, (T) + 2); ST_B((BUF), 0, 1, (T) + 2); }            \
        PBAR(); LGKM0();                                                                \
        __builtin_amdgcn_s_setprio(1);                                                  \
        _Pragma("unroll") for (int j = 0; j < 2; ++j)                                   \
        _Pragma("unroll") for (int i = 0; i < 4; ++i) {                                 \
            acc[i + 4][j] = __builtin_amdgcn_mfma_f32_16x16x32_bf16(a0[i], b00[j], acc[i + 4][j], 0, 0, 0); \
            acc[i + 4][j] = __builtin_amdgcn_mfma_f32_16x16x32_bf16(a1[i], b01[j], acc[i + 4][j], 0, 0, 0); \
        }                                                                               \
        __builtin_amdgcn_s_setprio(0); PBAR();                                          \
        /* ---- phase 4: no reads; MFMA m1n1 (b10/b11 live) ---- */                     \
        if (DO2) { ST_B((BUF), 1, 0, (T) + 2); ST_B((BUF), 1, 1, (T) + 2); }            \
        PBAR();                                                                         \
        __builtin_amdgcn_s_setprio(1);                                                  \
        _Pragma("unroll") for (int j = 0; j < 2; ++j)                                   \
        _Pragma("unroll") for (int i = 0; i < 4; ++i) {                                 \
            acc[i + 4][j + 2] = __builtin_amdgcn_mfma_f32_16x16x32_bf16(a0[i], b10[j], acc[i + 4][j + 2], 0, 0, 0); \
            acc[i + 4][j + 2] = __builtin_amdgcn_mfma_f32_16x16x32_bf16(a1[i], b11[j], acc[i + 4][j + 2], 0, 0, 0); \
        }                                                                               \
        __builtin_amdgcn_s_setprio(0);                                                  \
    } while (0)

__global__ __launch_bounds__(512, 2) void gemm8_kernel(const unsigned short* __restrict__ Acat,
                                                       const unsigned short* __restrict__ Bt,
                                                       float* __restrict__ C) {
    __shared__ unsigned short lds[65536];   // 128 KiB: 2 buf x (A 256x64 + B 256x64) bf16

    // grid = 102 mtiles * 8 ntiles = 816 (816 % 8 == 0 -> simple bijective XCD swizzle)
    int wg  = blockIdx.x;
    int swz = (wg & 7) * 102 + (wg >> 3);
    int mt  = swz >> 3, nt = swz & 7;
    int m0  = mt * 256, n0 = nt * 256;

    int tid = threadIdx.x;
    int l   = tid & 63;
    int w   = tid >> 6;          // wave 0..7
    int wm  = w >> 2;            // 0..1 (M interleave-16)
    int wn  = w & 3;             // 0..3 (N interleave-16)
    int r16 = l & 15, kc = l >> 4, x = l & 7;
    int c0  = kc ^ x;            // swizzled chunk for k-step 0
    int c1  = (4 + kc) ^ x;      // swizzled chunk for k-step 1

    // per-thread pre-swizzled global stage bases (linear LDS dest => swizzle the source)
    int srow = tid >> 3;
    int sq   = (tid & 7) ^ (srow & 7);
    const unsigned short* aSt = Acat + (long)(m0 + srow) * K_DIM + sq * 8;
    const unsigned short* bSt = Bt   + (long)(n0 + srow) * K_DIM + sq * 8;

    f32x4 acc[8][4] = {};

    // prologue: tile0 full (8 loads) + tile1 A0,B0,B1 (6 loads); wait tile0 (vmcnt 6)
    ST_A(0, 0, 0, 0); ST_A(0, 0, 1, 0); ST_A(0, 1, 0, 0); ST_A(0, 1, 1, 0);
    ST_B(0, 0, 0, 0); ST_B(0, 0, 1, 0); ST_B(0, 1, 0, 0); ST_B(0, 1, 1, 0);
    ST_A(1, 0, 0, 1); ST_A(1, 0, 1, 1);
    ST_B(1, 0, 0, 1); ST_B(1, 0, 1, 1); ST_B(1, 1, 0, 1); ST_B(1, 1, 1, 1);
    VMC(6); PBAR();

    // main loop: tiles 0..29 (K tiles of 64; K=2048 -> 32 tiles), 2 tiles/iter
#pragma unroll 1
    for (int t = 0; t < 30; t += 2) {
        TILE(0, t, 1, 1);     VMC(6); PBAR();
        TILE(1, t + 1, 1, 1); VMC(6); PBAR();
    }
    // tile 30: only A-half1(31) still missing; then drain for tile 31
    TILE(0, 30, 1, 0); VMC(0); PBAR();
    // tile 31: no stages
    TILE(1, 31, 0, 0);

    // epilogue: C/D layout col=lane&15, row=(lane>>4)*4+q; frag (i,j) at rows i*32+wm*16,
    // cols j*64+wn*16
    int orow = m0 + wm * 16 + (l >> 4) * 4;
    int ocol = n0 + wn * 16 + (l & 15);
#pragma unroll
    for (int i = 0; i < 8; ++i)
#pragma unroll
        for (int j = 0; j < 4; ++j)
#pragma unroll
            for (int q = 0; q < 4; ++q)
                C[(long)(orow + i * 32 + q) * N_DIM + (ocol + j * 64)] = acc[i][j][q];
}

// ---------- fallback: correct (slow) fp32 tiled GEMM, used only if ws too small ----------
__global__ void naive_gemm_kernel(const float* __restrict__ A, const float* __restrict__ B,
                                  float* __restrict__ C, int M) {
    __shared__ float As[16][16];
    __shared__ float Bs[16][17];
    int tx = threadIdx.x, ty = threadIdx.y;
    int row = blockIdx.y * 16 + ty;
    int col = blockIdx.x * 16 + tx;
    float s = 0.f;
    for (int k0 = 0; k0 < K_DIM; k0 += 16) {
        As[ty][tx] = A[(long)row * K_DIM + k0 + tx];
        Bs[ty][tx] = B[(long)(k0 + ty) * N_DIM + col];
        __syncthreads();
#pragma unroll
        for (int t = 0; t < 16; ++t) s += As[ty][t] * Bs[t][tx];
        __syncthreads();
    }
    C[(long)row * N_DIM + col] = s;
}

// ---------- host launcher ----------
extern "C" void kernel_launch(void* const* d_in, const int* in_sizes, int n_in,
                              void* d_out, int out_size, void* d_ws, size_t ws_size,
                              hipStream_t stream) {
    static const int g_m[N_GROUPS]   = {4096, 2048, 1024, 8192, 512, 3072, 6144, 1024};
    static const int g_off[N_GROUPS] = {0, 4096, 6144, 7168, 15360, 15872, 18944, 25088};

    float* C = (float*)d_out;
    const size_t need = ((size_t)M_TOTAL * K_DIM + (size_t)N_DIM * K_DIM) * 2;

    if (ws_size >= need) {
        unsigned short* Acat = (unsigned short*)d_ws;
        unsigned short* Bt   = Acat + (size_t)M_TOTAL * K_DIM;

        for (int g = 0; g < N_GROUPS; ++g)
            cvt_a_kernel<<<g_m[g], 256, 0, stream>>>((const float*)d_in[g],
                                                     Acat + (size_t)g_off[g] * K_DIM);
        cvt_bt_kernel<<<dim3(N_DIM / 32, K_DIM / 32), dim3(32, 8), 0, stream>>>(
            (const float*)d_in[8], Bt);

        gemm8_kernel<<<(M_TOTAL / 256) * (N_DIM / 256), 512, 0, stream>>>(Acat, Bt, C);
    } else {
        for (int g = 0; g < N_GROUPS; ++g)
            naive_gemm_kernel<<<dim3(N_DIM / 16, g_m[g] / 16), dim3(16, 16), 0, stream>>>(
                (const float*)d_in[g], (const float*)d_in[8], C + (size_t)g_off[g] * N_DIM,
                g_m[g]);
    }
}